// Round 14
// baseline (357.842 us; speedup 1.0000x reference)
//
#include <hip/hip_runtime.h>

#define D 64
#define NEG_INF -9e15f
#define MAXK 16
#define BSH 6                 // bucket = 64 rows
#define BROWS 64
#define MAXNB 2048
#define SCAP 4096             // LDS sort capacity; bucket mean 3413, sigma 58 (+11s)
#define SBSH 4                // superbucket = 16 buckets = 1024 rows
#define MAXNSB 128
#define SBB 16                // part2 blocks per superbucket

// bf16 round-to-nearest-even helpers
__device__ __forceinline__ unsigned short f2bf(float f) {
    unsigned u = __float_as_uint(f);
    return (unsigned short)((u + 0x7FFFu + ((u >> 16) & 1u)) >> 16);
}
__device__ __forceinline__ float bf2f(unsigned short h) {
    return __uint_as_float(((unsigned)h) << 16);
}

// ---------- Phase 0: relation-space precompute ----------
__global__ void relpre_kernel(const float* __restrict__ fc_W, const float* __restrict__ fc_b,
                              const float* __restrict__ rel_emb,
                              float* __restrict__ w1r, float* __restrict__ w2r,
                              float* __restrict__ br) {
    int r = blockIdx.x;
    int j = threadIdx.x;
    const float* rr = rel_emb + r * D;
    float s1 = 0.f, s2 = 0.f;
    for (int d = 0; d < D; ++d) {
        float rv = rr[d];
        s1 += fc_W[j * D + d] * rv;
        s2 += fc_W[(D + j) * D + d] * rv;
    }
    w1r[r * D + j] = s1;
    w2r[r * D + j] = s2;
    if (j == 0) {
        float sb = 0.f;
        for (int d = 0; d < D; ++d) sb += fc_b[d] * rr[d];
        br[r] = sb;
    }
}

// ---------- Phase 1: GAT item embeddings, K=16 specialized ----------
__global__ void gat16_kernel(const float* __restrict__ item_emb, const float* __restrict__ ent_emb,
                             const int* __restrict__ kg_e, const int* __restrict__ kg_r,
                             const float* __restrict__ w1r, const float* __restrict__ w2r,
                             const float* __restrict__ br,
                             float* __restrict__ x_items, unsigned short* __restrict__ xb_items,
                             int I, int pad_id) {
    const int K = 16;
    int wave = (blockIdx.x * blockDim.x + threadIdx.x) >> 6;
    int lane = threadIdx.x & 63;
    if (wave >= I) return;
    int i = wave;
    float itemv = item_emb[i * D + lane];
    float entv[16], pp[16], brv[16];
    int eidx_[16];
    #pragma unroll
    for (int k = 0; k < K; ++k) {
        int eidx = kg_e[i * K + k];
        int r = kg_r[i * K + k];
        eidx_[k] = eidx;
        float ev = ent_emb[(long)eidx * D + lane];
        entv[k] = ev;
        pp[k] = itemv * w1r[r * D + lane] + ev * w2r[r * D + lane];
        brv[k] = br[r];
    }
    float e[16];
    #pragma unroll
    for (int k = 0; k < K; ++k) {
        float p = pp[k];
        #pragma unroll
        for (int off = 32; off > 0; off >>= 1) p += __shfl_xor(p, off, 64);
        p += brv[k];
        p = p > 0.f ? p : 0.2f * p;
        if (eidx_[k] == pad_id) p = NEG_INF;
        e[k] = p;
    }
    float m = e[0];
    #pragma unroll
    for (int k = 1; k < K; ++k) m = fmaxf(m, e[k]);
    float s = 0.f;
    float att[16];
    #pragma unroll
    for (int k = 0; k < K; ++k) { att[k] = expf(e[k] - m); s += att[k]; }
    float inv = 1.f / s;
    float o = itemv;
    #pragma unroll
    for (int k = 0; k < K; ++k) o += att[k] * inv * entv[k];
    x_items[(long)i * D + lane] = o;
    if (xb_items) xb_items[(long)i * D + lane] = f2bf(o);
}

// ---------- Phase 1 fallback: generic K ----------
__global__ void gat_kernel(const float* __restrict__ item_emb, const float* __restrict__ ent_emb,
                           const int* __restrict__ kg_e, const int* __restrict__ kg_r,
                           const float* __restrict__ w1r, const float* __restrict__ w2r,
                           const float* __restrict__ br,
                           float* __restrict__ x_items, unsigned short* __restrict__ xb_items,
                           int I, int K, int pad_id) {
    int wave = (blockIdx.x * blockDim.x + threadIdx.x) >> 6;
    int lane = threadIdx.x & 63;
    if (wave >= I) return;
    int i = wave;
    float itemv = item_emb[i * D + lane];
    float entv[MAXK];
    float e[MAXK];
    for (int k = 0; k < K; ++k) {
        int eidx = kg_e[i * K + k];
        int r = kg_r[i * K + k];
        float ev = ent_emb[(long)eidx * D + lane];
        entv[k] = ev;
        float p = itemv * w1r[r * D + lane] + ev * w2r[r * D + lane];
        #pragma unroll
        for (int off = 32; off > 0; off >>= 1) p += __shfl_xor(p, off, 64);
        p += br[r];
        p = p > 0.f ? p : 0.2f * p;
        if (eidx == pad_id) p = NEG_INF;
        e[k] = p;
    }
    float m = e[0];
    for (int k = 1; k < K; ++k) m = fmaxf(m, e[k]);
    float s = 0.f;
    float att[MAXK];
    for (int k = 0; k < K; ++k) { att[k] = expf(e[k] - m); s += att[k]; }
    float inv = 1.f / s;
    float o = itemv;
    for (int k = 0; k < K; ++k) o += att[k] * inv * entv[k];
    x_items[(long)i * D + lane] = o;
    if (xb_items) xb_items[(long)i * D + lane] = f2bf(o);
}

// ---------- Fused: copy user half of x0 (+ bf16 mirror) + mark/compact batch rows ----------
__global__ void initmark_kernel(const float* __restrict__ user_emb, float* __restrict__ x0,
                                unsigned short* __restrict__ xb,
                                const int* __restrict__ users, const int* __restrict__ items,
                                int* __restrict__ flags, int* __restrict__ rowlist,
                                int* __restrict__ nlist, int U, int B, int n4) {
    int i = blockIdx.x * blockDim.x + threadIdx.x;
    if (i < n4) {
        float4 v = ((const float4*)user_emb)[i];
        ((float4*)x0)[i] = v;
        if (xb) {
            ushort4 m;
            m.x = f2bf(v.x); m.y = f2bf(v.y); m.z = f2bf(v.z); m.w = f2bf(v.w);
            ((ushort4*)xb)[i] = m;
        }
    }
    if (i < B) {
        int r1 = users[i];
        if (atomicExch(&flags[r1], 1) == 0) rowlist[atomicAdd(nlist, 1)] = r1;
        int r2 = U + items[i];
        if (atomicExch(&flags[r2], 1) == 0) rowlist[atomicAdd(nlist, 1)] = r2;
    }
}

// ---------- init (legacy mode): x users + acc = x ----------
__global__ void init_kernel(const float* __restrict__ user_emb,
                            float* __restrict__ x, float* __restrict__ acc,
                            int UD, int ND) {
    for (int idx = blockIdx.x * blockDim.x + threadIdx.x; idx < ND;
         idx += gridDim.x * blockDim.x) {
        float v = (idx < UD) ? user_emb[idx] : x[idx];
        x[idx] = v;
        acc[idx] = v;
    }
}

// ---------- mark (legacy mode) ----------
__global__ void mark_kernel(const int* __restrict__ users, const int* __restrict__ items,
                            int* __restrict__ flags, int* __restrict__ rowlist,
                            int* __restrict__ nlist, int U, int B) {
    int i = blockIdx.x * blockDim.x + threadIdx.x;
    if (i >= B) return;
    int r1 = users[i];
    if (atomicExch(&flags[r1], 1) == 0) rowlist[atomicAdd(nlist, 1)] = r1;
    int r2 = U + items[i];
    if (atomicExch(&flags[r2], 1) == 0) rowlist[atomicAdd(nlist, 1)] = r2;
}

// ---------- Bucket histogram (LDS-staged) ----------
__global__ void bhist_kernel(const int* __restrict__ rows, int* __restrict__ bcnt,
                             int n_edges, int NB) {
    __shared__ int h[MAXNB];
    for (int i = threadIdx.x; i < NB; i += blockDim.x) h[i] = 0;
    __syncthreads();
    for (int e = blockIdx.x * blockDim.x + threadIdx.x; e < n_edges;
         e += gridDim.x * blockDim.x)
        atomicAdd(&h[rows[e] >> BSH], 1);
    __syncthreads();
    for (int i = threadIdx.x; i < NB; i += blockDim.x)
        if (h[i]) atomicAdd(&bcnt[i], h[i]);
}

// ---------- Bucket scan (single block, 1024 thr, up to 2048 entries) ----------
__global__ void bscan_kernel(const int* __restrict__ bcnt, int* __restrict__ bstart,
                             int* __restrict__ bfill, int* __restrict__ sbfill,
                             int NB, int n_edges) {
    __shared__ int bufA[MAXNB];
    __shared__ int bufB[MAXNB];
    int tid = threadIdx.x;
    int v0 = (tid < NB) ? bcnt[tid] : 0;
    int v1 = (tid + 1024 < NB) ? bcnt[tid + 1024] : 0;
    bufA[tid] = v0;
    bufA[tid + 1024] = v1;
    __syncthreads();
    int* src = bufA;
    int* dst = bufB;
    for (int off = 1; off < MAXNB; off <<= 1) {
        int j0 = tid, j1 = tid + 1024;
        dst[j0] = src[j0] + (j0 >= off ? src[j0 - off] : 0);
        dst[j1] = src[j1] + (j1 >= off ? src[j1 - off] : 0);
        __syncthreads();
        int* t = src; src = dst; dst = t;
    }
    if (tid < NB) {
        int ex = src[tid] - v0;
        bstart[tid] = ex;
        bfill[tid] = ex;
        if ((tid & ((1 << SBSH) - 1)) == 0) sbfill[tid >> SBSH] = ex;
    }
    if (tid + 1024 < NB) {
        int ex = src[tid + 1024] - v1;
        bstart[tid + 1024] = ex;
        bfill[tid + 1024] = ex;
        if (((tid + 1024) & ((1 << SBSH) - 1)) == 0) sbfill[(tid + 1024) >> SBSH] = ex;
    }
    if (tid == 0) bstart[NB] = n_edges;
}

// ---------- part1: scatter by SUPERBUCKET (1536 blocks: 6/CU, latency-hiding) ----
// payload = (valbits<<32) | ((row>>6)&15)<<26 | (row&63)<<20 | col
__global__ __launch_bounds__(256) void
part1_kernel(const int* __restrict__ rows, const int* __restrict__ cols,
             const float* __restrict__ vals,
             int* __restrict__ sbfill, long* __restrict__ etmp,
             int n_edges, int NSB) {
    __shared__ int h[MAXNSB];
    int nb_blocks = gridDim.x;
    int c0 = (int)((long)n_edges * blockIdx.x / nb_blocks);
    int c1 = (int)((long)n_edges * (blockIdx.x + 1) / nb_blocks);
    for (int i = threadIdx.x; i < NSB; i += blockDim.x) h[i] = 0;
    __syncthreads();
    for (int e = c0 + threadIdx.x; e < c1; e += blockDim.x)
        atomicAdd(&h[rows[e] >> (BSH + SBSH)], 1);
    __syncthreads();
    for (int i = threadIdx.x; i < NSB; i += blockDim.x)
        if (h[i]) h[i] = atomicAdd(&sbfill[i], h[i]);
    __syncthreads();
    for (int e = c0 + threadIdx.x; e < c1; e += blockDim.x) {
        int r = rows[e];
        int pos = atomicAdd(&h[r >> (BSH + SBSH)], 1);
        etmp[pos] = ((long)(unsigned)__float_as_int(vals[e]) << 32)
                  | (unsigned)(cols[e] | ((r & (BROWS - 1)) << 20)
                               | (((r >> BSH) & ((1 << SBSH) - 1)) << 26));
    }
}

// ---------- part2: within superbucket, scatter by BUCKET ----------
__global__ __launch_bounds__(256) void
part2_kernel(const long* __restrict__ etmp, const int* __restrict__ bstart,
             int* __restrict__ bfill, long* __restrict__ edges2, int NB) {
    __shared__ int h[1 << SBSH];
    int sb = blockIdx.x / SBB;
    int j  = blockIdx.x % SBB;
    int b0 = sb << SBSH;
    int b1 = b0 + (1 << SBSH); if (b1 > NB) b1 = NB;
    int s = bstart[b0];
    int t = bstart[b1];
    int m = t - s;
    int c0 = s + (int)((long)m * j / SBB);
    int c1 = s + (int)((long)m * (j + 1) / SBB);
    if (threadIdx.x < (1 << SBSH)) h[threadIdx.x] = 0;
    __syncthreads();
    for (int e = c0 + threadIdx.x; e < c1; e += blockDim.x)
        atomicAdd(&h[((int)etmp[e] >> 26) & ((1 << SBSH) - 1)], 1);
    __syncthreads();
    if (threadIdx.x < (1 << SBSH)) {
        int c = h[threadIdx.x];
        if (c) h[threadIdx.x] = atomicAdd(&bfill[b0 + threadIdx.x], c);
    }
    __syncthreads();
    for (int e = c0 + threadIdx.x; e < c1; e += blockDim.x) {
        long v = etmp[e];
        int pos = atomicAdd(&h[((int)v >> 26) & ((1 << SBSH) - 1)], 1);
        edges2[pos] = v;
    }
}

// ---------- legacy single-pass partition (small-ws fallback) ----------
__global__ __launch_bounds__(256) void
part_legacy_kernel(const int* __restrict__ rows, const int* __restrict__ cols,
                   const float* __restrict__ vals,
                   int* __restrict__ bfill, long* __restrict__ etmp,
                   int n_edges, int NB) {
    __shared__ int h[MAXNB];
    int nb_blocks = gridDim.x;
    int c0 = (int)((long)n_edges * blockIdx.x / nb_blocks);
    int c1 = (int)((long)n_edges * (blockIdx.x + 1) / nb_blocks);
    for (int i = threadIdx.x; i < NB; i += blockDim.x) h[i] = 0;
    __syncthreads();
    for (int e = c0 + threadIdx.x; e < c1; e += blockDim.x)
        atomicAdd(&h[rows[e] >> BSH], 1);
    __syncthreads();
    for (int i = threadIdx.x; i < NB; i += blockDim.x)
        if (h[i]) h[i] = atomicAdd(&bfill[i], h[i]);
    __syncthreads();
    for (int e = c0 + threadIdx.x; e < c1; e += blockDim.x) {
        int r = rows[e];
        int pos = atomicAdd(&h[r >> BSH], 1);
        etmp[pos] = ((long)(unsigned)__float_as_int(vals[e]) << 32)
                  | (unsigned)(cols[e] | ((r & (BROWS - 1)) << 20));
    }
}

// ---------- In-bucket counting sort -> exact CSR (single global read) ----------
__global__ __launch_bounds__(256) void
sort_kernel(const long* __restrict__ ein, const int* __restrict__ bstart,
            long* __restrict__ edges, int* __restrict__ row_start,
            int* __restrict__ cnt, int N) {
    __shared__ long obuf[SCAP];
    __shared__ int h[BROWS];
    __shared__ int fill[BROWS];
    int b = blockIdx.x;
    int s = bstart[b];
    int t = bstart[b + 1];
    int m = t - s;
    int tid = threadIdx.x;
    if (tid < BROWS) h[tid] = 0;
    __syncthreads();
    int row0 = b << BSH;
    if (m <= SCAP) {
        for (int i = tid; i < m; i += 256) {
            long v = ein[s + i];
            obuf[i] = v;
            atomicAdd(&h[((int)v >> 20) & (BROWS - 1)], 1);
        }
        __syncthreads();
        if (tid < BROWS) fill[tid] = h[tid];
        __syncthreads();
        for (int o = 1; o < BROWS; o <<= 1) {
            int v = (tid < BROWS && tid >= o) ? fill[tid - o] : 0;
            __syncthreads();
            if (tid < BROWS) fill[tid] += v;
            __syncthreads();
        }
        if (tid < BROWS) {
            int ex = fill[tid] - h[tid];
            int row = row0 + tid;
            if (row < N) { row_start[row] = s + ex; cnt[row] = h[tid]; }
            fill[tid] = s + ex;
        }
        __syncthreads();
        for (int i = tid; i < m; i += 256) {
            long v = obuf[i];
            int r = ((int)v >> 20) & (BROWS - 1);
            edges[atomicAdd(&fill[r], 1)] = v;
        }
    } else {
        for (int i = tid; i < m; i += 256)
            atomicAdd(&h[((int)ein[s + i] >> 20) & (BROWS - 1)], 1);
        __syncthreads();
        if (tid < BROWS) fill[tid] = h[tid];
        __syncthreads();
        for (int o = 1; o < BROWS; o <<= 1) {
            int v = (tid < BROWS && tid >= o) ? fill[tid - o] : 0;
            __syncthreads();
            if (tid < BROWS) fill[tid] += v;
            __syncthreads();
        }
        if (tid < BROWS) {
            int ex = fill[tid] - h[tid];
            int row = row0 + tid;
            if (row < N) { row_start[row] = s + ex; cnt[row] = h[tid]; }
            fill[tid] = s + ex;
        }
        __syncthreads();
        for (int i = tid; i < m; i += 256) {
            long v = ein[s + i];
            int r = ((int)v >> 20) & (BROWS - 1);
            edges[atomicAdd(&fill[r], 1)] = v;
        }
    }
}

// ---------- Phase 2b (bf16): CSR SpMV, wave per row, bf16 gather mirror ----------
__global__ __launch_bounds__(256) void
spmv_bf_kernel(const long* __restrict__ edges, const int* __restrict__ row_start,
               const int* __restrict__ cnt, const unsigned short* __restrict__ xb,
               float* __restrict__ nxt, unsigned short* __restrict__ xbn, int N) {
    int wid = (int)((long)blockIdx.x * blockDim.x + threadIdx.x) >> 6;
    int row = __builtin_amdgcn_readfirstlane(wid);
    int lane = threadIdx.x & 63;
    if (row >= N) return;
    int s = __builtin_amdgcn_readfirstlane(row_start[row]);
    int n = __builtin_amdgcn_readfirstlane(cnt[row]);
    const long* ep = edges + s;
    float sum = 0.f;
    int e = 0;
    for (; e + 16 <= n; e += 16) {
        long q[16];
        float g[16];
        #pragma unroll
        for (int j = 0; j < 16; ++j) q[j] = ep[e + j];
        #pragma unroll
        for (int j = 0; j < 16; ++j)
            g[j] = bf2f(xb[(long)((int)q[j] & 0xFFFFF) * D + lane]);
        #pragma unroll
        for (int j = 0; j < 16; ++j) sum += __int_as_float((int)(q[j] >> 32)) * g[j];
    }
    for (; e + 4 <= n; e += 4) {
        long q[4];
        float g[4];
        #pragma unroll
        for (int j = 0; j < 4; ++j) q[j] = ep[e + j];
        #pragma unroll
        for (int j = 0; j < 4; ++j)
            g[j] = bf2f(xb[(long)((int)q[j] & 0xFFFFF) * D + lane]);
        #pragma unroll
        for (int j = 0; j < 4; ++j) sum += __int_as_float((int)(q[j] >> 32)) * g[j];
    }
    for (; e < n; ++e) {
        long q = ep[e];
        sum += __int_as_float((int)(q >> 32)) * bf2f(xb[(long)((int)q & 0xFFFFF) * D + lane]);
    }
    long o = (long)row * D + lane;
    __builtin_nontemporal_store(sum, &nxt[o]);
    xbn[o] = f2bf(sum);
}

// ---------- Phase 2c (bf16): sparse layer 3, wave per LISTED row ----------
__global__ __launch_bounds__(256) void
spmv_list_bf_kernel(const long* __restrict__ edges, const int* __restrict__ row_start,
                    const int* __restrict__ cnt, const int* __restrict__ rowlist,
                    const int* __restrict__ nlist, const unsigned short* __restrict__ xb,
                    float* __restrict__ nxt) {
    int wid = (int)((long)blockIdx.x * blockDim.x + threadIdx.x) >> 6;
    int nl = __builtin_amdgcn_readfirstlane(nlist[0]);
    if (wid >= nl) return;
    int row = __builtin_amdgcn_readfirstlane(rowlist[wid]);
    int lane = threadIdx.x & 63;
    int s = __builtin_amdgcn_readfirstlane(row_start[row]);
    int n = __builtin_amdgcn_readfirstlane(cnt[row]);
    const long* ep = edges + s;
    float sum = 0.f;
    int e = 0;
    for (; e + 16 <= n; e += 16) {
        long q[16];
        float g[16];
        #pragma unroll
        for (int j = 0; j < 16; ++j) q[j] = ep[e + j];
        #pragma unroll
        for (int j = 0; j < 16; ++j)
            g[j] = bf2f(xb[(long)((int)q[j] & 0xFFFFF) * D + lane]);
        #pragma unroll
        for (int j = 0; j < 16; ++j) sum += __int_as_float((int)(q[j] >> 32)) * g[j];
    }
    for (; e + 4 <= n; e += 4) {
        long q[4];
        float g[4];
        #pragma unroll
        for (int j = 0; j < 4; ++j) q[j] = ep[e + j];
        #pragma unroll
        for (int j = 0; j < 4; ++j)
            g[j] = bf2f(xb[(long)((int)q[j] & 0xFFFFF) * D + lane]);
        #pragma unroll
        for (int j = 0; j < 4; ++j) sum += __int_as_float((int)(q[j] >> 32)) * g[j];
    }
    for (; e < n; ++e) {
        long q = ep[e];
        sum += __int_as_float((int)(q >> 32)) * bf2f(xb[(long)((int)q & 0xFFFFF) * D + lane]);
    }
    __builtin_nontemporal_store(sum, &nxt[(long)row * D + lane]);
}

// ---------- Phase 2b (f32 fallback): CSR SpMV, wave per row ----------
__global__ __launch_bounds__(256) void
spmv_kernel(const long* __restrict__ edges, const int* __restrict__ row_start,
            const int* __restrict__ cnt, const float* __restrict__ x,
            float* __restrict__ nxt, float* __restrict__ acc, int N) {
    int wid = (int)((long)blockIdx.x * blockDim.x + threadIdx.x) >> 6;
    int row = __builtin_amdgcn_readfirstlane(wid);
    int lane = threadIdx.x & 63;
    if (row >= N) return;
    int s = __builtin_amdgcn_readfirstlane(row_start[row]);
    int n = __builtin_amdgcn_readfirstlane(cnt[row]);
    const long* ep = edges + s;
    float sum = 0.f;
    int e = 0;
    for (; e + 16 <= n; e += 16) {
        long q[16];
        float g[16];
        #pragma unroll
        for (int j = 0; j < 16; ++j) q[j] = ep[e + j];
        #pragma unroll
        for (int j = 0; j < 16; ++j) g[j] = x[(long)((int)q[j] & 0xFFFFF) * D + lane];
        #pragma unroll
        for (int j = 0; j < 16; ++j) sum += __int_as_float((int)(q[j] >> 32)) * g[j];
    }
    for (; e + 4 <= n; e += 4) {
        long q[4];
        float g[4];
        #pragma unroll
        for (int j = 0; j < 4; ++j) q[j] = ep[e + j];
        #pragma unroll
        for (int j = 0; j < 4; ++j) g[j] = x[(long)((int)q[j] & 0xFFFFF) * D + lane];
        #pragma unroll
        for (int j = 0; j < 4; ++j) sum += __int_as_float((int)(q[j] >> 32)) * g[j];
    }
    for (; e < n; ++e) {
        long q = ep[e];
        sum += __int_as_float((int)(q >> 32)) * x[(long)((int)q & 0xFFFFF) * D + lane];
    }
    long o = (long)row * D + lane;
    if (acc) { nxt[o] = sum; acc[o] += sum; }
    else __builtin_nontemporal_store(sum, &nxt[o]);
}

// ---------- Phase 2c (f32 fallback): sparse layer 3 ----------
__global__ __launch_bounds__(256) void
spmv_list_kernel(const long* __restrict__ edges, const int* __restrict__ row_start,
                 const int* __restrict__ cnt, const int* __restrict__ rowlist,
                 const int* __restrict__ nlist, const float* __restrict__ x,
                 float* __restrict__ nxt, float* __restrict__ acc) {
    int wid = (int)((long)blockIdx.x * blockDim.x + threadIdx.x) >> 6;
    int nl = __builtin_amdgcn_readfirstlane(nlist[0]);
    if (wid >= nl) return;
    int row = __builtin_amdgcn_readfirstlane(rowlist[wid]);
    int lane = threadIdx.x & 63;
    int s = __builtin_amdgcn_readfirstlane(row_start[row]);
    int n = __builtin_amdgcn_readfirstlane(cnt[row]);
    const long* ep = edges + s;
    float sum = 0.f;
    int e = 0;
    for (; e + 16 <= n; e += 16) {
        long q[16];
        float g[16];
        #pragma unroll
        for (int j = 0; j < 16; ++j) q[j] = ep[e + j];
        #pragma unroll
        for (int j = 0; j < 16; ++j) g[j] = x[(long)((int)q[j] & 0xFFFFF) * D + lane];
        #pragma unroll
        for (int j = 0; j < 16; ++j) sum += __int_as_float((int)(q[j] >> 32)) * g[j];
    }
    for (; e + 4 <= n; e += 4) {
        long q[4];
        float g[4];
        #pragma unroll
        for (int j = 0; j < 4; ++j) q[j] = ep[e + j];
        #pragma unroll
        for (int j = 0; j < 4; ++j) g[j] = x[(long)((int)q[j] & 0xFFFFF) * D + lane];
        #pragma unroll
        for (int j = 0; j < 4; ++j) sum += __int_as_float((int)(q[j] >> 32)) * g[j];
    }
    for (; e < n; ++e) {
        long q = ep[e];
        sum += __int_as_float((int)(q >> 32)) * x[(long)((int)q & 0xFFFFF) * D + lane];
    }
    long o = (long)row * D + lane;
    if (acc) { nxt[o] = sum; acc[o] += sum; }
    else __builtin_nontemporal_store(sum, &nxt[o]);
}

// ---------- Phase 3: gamma = dot of layer-mean embeddings ----------
__global__ void dot_kernel(const float* __restrict__ x0, const float* __restrict__ x1,
                           const float* __restrict__ x2, const float* __restrict__ x3,
                           const float* __restrict__ acc,
                           const int* __restrict__ users, const int* __restrict__ items,
                           float* __restrict__ out, int U, int B) {
    int wave = (blockIdx.x * blockDim.x + threadIdx.x) >> 6;
    int lane = threadIdx.x & 63;
    if (wave >= B) return;
    long ou = (long)users[wave] * D + lane;
    long oi = (long)(U + items[wave]) * D + lane;
    float su, si;
    if (acc) {
        su = acc[ou];
        si = acc[oi];
    } else {
        su = x0[ou] + x1[ou] + x2[ou] + x3[ou];
        si = x0[oi] + x1[oi] + x2[oi] + x3[oi];
    }
    float p = su * si;
    #pragma unroll
    for (int off = 32; off > 0; off >>= 1) p += __shfl_xor(p, off, 64);
    if (lane == 0) out[wave] = p * 0.0625f;
}

extern "C" void kernel_launch(void* const* d_in, const int* in_sizes, int n_in,
                              void* d_out, int out_size, void* d_ws, size_t ws_size,
                              hipStream_t stream) {
    const int*   users    = (const int*)  d_in[0];
    const int*   items    = (const int*)  d_in[1];
    const int*   g_rows   = (const int*)  d_in[2];
    const int*   g_cols   = (const int*)  d_in[3];
    const float* g_vals   = (const float*)d_in[4];
    const float* user_emb = (const float*)d_in[5];
    const float* item_emb = (const float*)d_in[6];
    const float* ent_emb  = (const float*)d_in[7];
    const float* rel_emb  = (const float*)d_in[8];
    const int*   kg_e     = (const int*)  d_in[9];
    const int*   kg_r     = (const int*)  d_in[10];
    const float* fc_W     = (const float*)d_in[11];
    const float* fc_b     = (const float*)d_in[12];
    float* out = (float*)d_out;

    int B       = in_sizes[0];
    int n_edges = in_sizes[2];
    int U       = in_sizes[5] / D;
    int I       = in_sizes[6] / D;
    int NE1     = in_sizes[7] / D;   // E_ENT + 1
    int NR      = in_sizes[8] / D;   // R + 1
    int K       = in_sizes[9] / I;
    int N  = U + I;
    int ND = N * D;
    int NB = (N + BROWS - 1) >> BSH;       // 1172 buckets (<= MAXNB)
    int NSB = (NB + (1 << SBSH) - 1) >> SBSH;  // 74 superbuckets (<= MAXNSB)

    size_t small = (size_t)(2 * NR * D + NR + 3 * (NB + 1) + MAXNSB + 4 * N + 1) * 4 + 8192;
    size_t need_def = 4ul * ND * 4 + (size_t)n_edges * 8 + small;
    size_t need_bf  = need_def + 2ul * ND * 2 + 512;
    int deferred = (need_def <= ws_size);
    int usebf    = (need_bf <= ws_size);

    char* basep = (char*)d_ws;
    size_t woff = 0;
    auto alloc = [&](size_t bytes) -> char* {
        char* p = basep + woff;
        woff = (woff + bytes + 255) & ~(size_t)255;
        return p;
    };

    float *x0, *x1, *x2, *x3, *acc;
    long *etmp, *edges2;
    unsigned short *xb0 = nullptr, *xb1 = nullptr;
    if (deferred) {
        x0 = (float*)alloc((size_t)ND * 4);
        x1 = (float*)alloc((size_t)ND * 4);
        x2 = (float*)alloc((size_t)ND * 4);
        x3 = (float*)alloc((size_t)ND * 4);
        acc = nullptr;
        etmp   = (long*)x0;             // x0+x1 span 38.4MB >= 32MB; dead after part2
        edges2 = (long*)x2;             // x2+x3 span; dead after sort
        if (usebf) {
            xb0 = (unsigned short*)alloc((size_t)ND * 2);
            xb1 = (unsigned short*)alloc((size_t)ND * 2);
        }
    } else {
        x0 = (float*)alloc((size_t)ND * 4);
        x1 = (float*)alloc((size_t)ND * 4);
        x2 = x0; x3 = x1;               // ping-pong
        acc = (float*)alloc((size_t)ND * 4);
        etmp   = (long*)x0;
        edges2 = nullptr;
        usebf = 0;
    }
    float* w1r      = (float*)alloc((size_t)NR * D * 4);
    float* w2r      = (float*)alloc((size_t)NR * D * 4);
    float* br       = (float*)alloc((size_t)NR * 4);
    int*   bcnt     = (int*)  alloc((size_t)(NB + 1) * 4);
    int*   bstart   = (int*)  alloc((size_t)(NB + 1) * 4);
    int*   bfill    = (int*)  alloc((size_t)(NB + 1) * 4);
    int*   sbfill   = (int*)  alloc((size_t)MAXNSB * 4);
    int*   row_start= (int*)  alloc((size_t)N * 4);
    int*   cnt      = (int*)  alloc((size_t)N * 4);
    int*   flags    = (int*)  alloc((size_t)(N + 1) * 4);  // +1: nlist counter
    int*   rowlist  = (int*)  alloc((size_t)N * 4);
    int*   nlist    = flags + N;
    long*  edges    = (long*) alloc((size_t)n_edges * 8);

    // ---- CSR build (etmp/edges2 occupy layer-buffer space; runs first) ----
    hipMemsetAsync(bcnt, 0, (size_t)(NB + 1) * 4, stream);
    bhist_kernel<<<1024, 256, 0, stream>>>(g_rows, bcnt, n_edges, NB);
    bscan_kernel<<<1, 1024, 0, stream>>>(bcnt, bstart, bfill, sbfill, NB, n_edges);
    if (deferred) {
        part1_kernel<<<1536, 256, 0, stream>>>(g_rows, g_cols, g_vals, sbfill, etmp,
                                               n_edges, NSB);
        part2_kernel<<<NSB * SBB, 256, 0, stream>>>(etmp, bstart, bfill, edges2, NB);
        sort_kernel<<<NB, 256, 0, stream>>>(edges2, bstart, edges, row_start, cnt, N);
    } else {
        part_legacy_kernel<<<512, 256, 0, stream>>>(g_rows, g_cols, g_vals, bfill, etmp,
                                                    n_edges, NB);
        sort_kernel<<<NB, 256, 0, stream>>>(etmp, bstart, edges, row_start, cnt, N);
    }

    // ---- flags/rowlist zero (for mark) ----
    hipMemsetAsync(flags, 0, (size_t)(N + 1) * 4, stream);

    // Phase 0 + 1: GAT (writes x0 items f32 + bf16 mirror in bf mode)
    relpre_kernel<<<NR, D, 0, stream>>>(fc_W, fc_b, rel_emb, w1r, w2r, br);
    unsigned short* xb_items = usebf ? xb0 + (long)U * D : nullptr;
    if (K == 16) {
        gat16_kernel<<<(I + 3) / 4, 256, 0, stream>>>(item_emb, ent_emb, kg_e, kg_r,
                                                      w1r, w2r, br,
                                                      x0 + (long)U * D, xb_items, I, NE1 - 1);
    } else {
        gat_kernel<<<(I + 3) / 4, 256, 0, stream>>>(item_emb, ent_emb, kg_e, kg_r,
                                                    w1r, w2r, br,
                                                    x0 + (long)U * D, xb_items, I, K, NE1 - 1);
    }

    // Phase 2a: user half of x0 (+ mirror) + batch-row mark/compact
    if (deferred) {
        int n4 = U * D / 4;
        int g = n4 > B ? n4 : B;
        initmark_kernel<<<(g + 255) / 256, 256, 0, stream>>>(user_emb, x0,
                                                             usebf ? xb0 : nullptr,
                                                             users, items,
                                                             flags, rowlist, nlist, U, B, n4);
    } else {
        init_kernel<<<2048, 256, 0, stream>>>(user_emb, x0, acc, U * D, ND);
        mark_kernel<<<(B + 255) / 256, 256, 0, stream>>>(users, items, flags, rowlist,
                                                         nlist, U, B);
    }

    // Phase 2b/2c: LightGCN layers
    long total = (long)N * 64;
    int blocks = (int)((total + 255) / 256);
    int maxrows = (2 * B < N) ? 2 * B : N;
    int lblocks = (int)(((long)maxrows * 64 + 255) / 256);
    if (usebf) {
        spmv_bf_kernel<<<blocks, 256, 0, stream>>>(edges, row_start, cnt, xb0, x1, xb1, N);
        spmv_bf_kernel<<<blocks, 256, 0, stream>>>(edges, row_start, cnt, xb1, x2, xb0, N);
        spmv_list_bf_kernel<<<lblocks, 256, 0, stream>>>(edges, row_start, cnt, rowlist,
                                                         nlist, xb0, x3);
    } else {
        spmv_kernel<<<blocks, 256, 0, stream>>>(edges, row_start, cnt, x0, x1, acc, N);
        spmv_kernel<<<blocks, 256, 0, stream>>>(edges, row_start, cnt, x1, x2, acc, N);
        spmv_list_kernel<<<lblocks, 256, 0, stream>>>(edges, row_start, cnt, rowlist, nlist,
                                                      x2, x3, acc);
    }

    // Phase 3: batch dot (f32 layer buffers, unchanged)
    dot_kernel<<<(B + 3) / 4, 256, 0, stream>>>(x0, x1, x2, x3, acc, users, items, out, U, B);
}

// Round 15
// 338.827 us; speedup vs baseline: 1.0561x; 1.0561x over previous
//
#include <hip/hip_runtime.h>

#define D 64
#define NEG_INF -9e15f
#define MAXK 16
#define BSH 6                 // bucket = 64 rows
#define BROWS 64
#define MAXNB 2048
#define SCAP 4096             // LDS sort capacity; bucket mean 3413, sigma 58 (+11s)
#define SBSH 4                // superbucket = 16 buckets = 1024 rows
#define MAXNSB 128
#define SBB 8                 // part2 blocks per superbucket (R12 proven)

// bf16 round-to-nearest-even helpers
__device__ __forceinline__ unsigned short f2bf(float f) {
    unsigned u = __float_as_uint(f);
    return (unsigned short)((u + 0x7FFFu + ((u >> 16) & 1u)) >> 16);
}
__device__ __forceinline__ float bf2f(unsigned short h) {
    return __uint_as_float(((unsigned)h) << 16);
}

// ---------- Phase 0: relation-space precompute ----------
__global__ void relpre_kernel(const float* __restrict__ fc_W, const float* __restrict__ fc_b,
                              const float* __restrict__ rel_emb,
                              float* __restrict__ w1r, float* __restrict__ w2r,
                              float* __restrict__ br) {
    int r = blockIdx.x;
    int j = threadIdx.x;
    const float* rr = rel_emb + r * D;
    float s1 = 0.f, s2 = 0.f;
    for (int d = 0; d < D; ++d) {
        float rv = rr[d];
        s1 += fc_W[j * D + d] * rv;
        s2 += fc_W[(D + j) * D + d] * rv;
    }
    w1r[r * D + j] = s1;
    w2r[r * D + j] = s2;
    if (j == 0) {
        float sb = 0.f;
        for (int d = 0; d < D; ++d) sb += fc_b[d] * rr[d];
        br[r] = sb;
    }
}

// ---------- Phase 1: GAT item embeddings, K=16 specialized ----------
__global__ void gat16_kernel(const float* __restrict__ item_emb, const float* __restrict__ ent_emb,
                             const int* __restrict__ kg_e, const int* __restrict__ kg_r,
                             const float* __restrict__ w1r, const float* __restrict__ w2r,
                             const float* __restrict__ br,
                             float* __restrict__ x_items, unsigned short* __restrict__ xb_items,
                             int I, int pad_id) {
    const int K = 16;
    int wave = (blockIdx.x * blockDim.x + threadIdx.x) >> 6;
    int lane = threadIdx.x & 63;
    if (wave >= I) return;
    int i = wave;
    float itemv = item_emb[i * D + lane];
    float entv[16], pp[16], brv[16];
    int eidx_[16];
    #pragma unroll
    for (int k = 0; k < K; ++k) {
        int eidx = kg_e[i * K + k];
        int r = kg_r[i * K + k];
        eidx_[k] = eidx;
        float ev = ent_emb[(long)eidx * D + lane];
        entv[k] = ev;
        pp[k] = itemv * w1r[r * D + lane] + ev * w2r[r * D + lane];
        brv[k] = br[r];
    }
    float e[16];
    #pragma unroll
    for (int k = 0; k < K; ++k) {
        float p = pp[k];
        #pragma unroll
        for (int off = 32; off > 0; off >>= 1) p += __shfl_xor(p, off, 64);
        p += brv[k];
        p = p > 0.f ? p : 0.2f * p;
        if (eidx_[k] == pad_id) p = NEG_INF;
        e[k] = p;
    }
    float m = e[0];
    #pragma unroll
    for (int k = 1; k < K; ++k) m = fmaxf(m, e[k]);
    float s = 0.f;
    float att[16];
    #pragma unroll
    for (int k = 0; k < K; ++k) { att[k] = expf(e[k] - m); s += att[k]; }
    float inv = 1.f / s;
    float o = itemv;
    #pragma unroll
    for (int k = 0; k < K; ++k) o += att[k] * inv * entv[k];
    x_items[(long)i * D + lane] = o;
    if (xb_items) xb_items[(long)i * D + lane] = f2bf(o);
}

// ---------- Phase 1 fallback: generic K ----------
__global__ void gat_kernel(const float* __restrict__ item_emb, const float* __restrict__ ent_emb,
                           const int* __restrict__ kg_e, const int* __restrict__ kg_r,
                           const float* __restrict__ w1r, const float* __restrict__ w2r,
                           const float* __restrict__ br,
                           float* __restrict__ x_items, unsigned short* __restrict__ xb_items,
                           int I, int K, int pad_id) {
    int wave = (blockIdx.x * blockDim.x + threadIdx.x) >> 6;
    int lane = threadIdx.x & 63;
    if (wave >= I) return;
    int i = wave;
    float itemv = item_emb[i * D + lane];
    float entv[MAXK];
    float e[MAXK];
    for (int k = 0; k < K; ++k) {
        int eidx = kg_e[i * K + k];
        int r = kg_r[i * K + k];
        float ev = ent_emb[(long)eidx * D + lane];
        entv[k] = ev;
        float p = itemv * w1r[r * D + lane] + ev * w2r[r * D + lane];
        #pragma unroll
        for (int off = 32; off > 0; off >>= 1) p += __shfl_xor(p, off, 64);
        p += br[r];
        p = p > 0.f ? p : 0.2f * p;
        if (eidx == pad_id) p = NEG_INF;
        e[k] = p;
    }
    float m = e[0];
    for (int k = 1; k < K; ++k) m = fmaxf(m, e[k]);
    float s = 0.f;
    float att[MAXK];
    for (int k = 0; k < K; ++k) { att[k] = expf(e[k] - m); s += att[k]; }
    float inv = 1.f / s;
    float o = itemv;
    for (int k = 0; k < K; ++k) o += att[k] * inv * entv[k];
    x_items[(long)i * D + lane] = o;
    if (xb_items) xb_items[(long)i * D + lane] = f2bf(o);
}

// ---------- Fused: copy user half of x0 (+ bf16 mirror) + mark/compact batch rows ----------
__global__ void initmark_kernel(const float* __restrict__ user_emb, float* __restrict__ x0,
                                unsigned short* __restrict__ xb,
                                const int* __restrict__ users, const int* __restrict__ items,
                                int* __restrict__ flags, int* __restrict__ rowlist,
                                int* __restrict__ nlist, int U, int B, int n4) {
    int i = blockIdx.x * blockDim.x + threadIdx.x;
    if (i < n4) {
        float4 v = ((const float4*)user_emb)[i];
        ((float4*)x0)[i] = v;
        if (xb) {
            ushort4 m;
            m.x = f2bf(v.x); m.y = f2bf(v.y); m.z = f2bf(v.z); m.w = f2bf(v.w);
            ((ushort4*)xb)[i] = m;
        }
    }
    if (i < B) {
        int r1 = users[i];
        if (atomicExch(&flags[r1], 1) == 0) rowlist[atomicAdd(nlist, 1)] = r1;
        int r2 = U + items[i];
        if (atomicExch(&flags[r2], 1) == 0) rowlist[atomicAdd(nlist, 1)] = r2;
    }
}

// ---------- init (legacy mode): x users + acc = x ----------
__global__ void init_kernel(const float* __restrict__ user_emb,
                            float* __restrict__ x, float* __restrict__ acc,
                            int UD, int ND) {
    for (int idx = blockIdx.x * blockDim.x + threadIdx.x; idx < ND;
         idx += gridDim.x * blockDim.x) {
        float v = (idx < UD) ? user_emb[idx] : x[idx];
        x[idx] = v;
        acc[idx] = v;
    }
}

// ---------- mark (legacy mode) ----------
__global__ void mark_kernel(const int* __restrict__ users, const int* __restrict__ items,
                            int* __restrict__ flags, int* __restrict__ rowlist,
                            int* __restrict__ nlist, int U, int B) {
    int i = blockIdx.x * blockDim.x + threadIdx.x;
    if (i >= B) return;
    int r1 = users[i];
    if (atomicExch(&flags[r1], 1) == 0) rowlist[atomicAdd(nlist, 1)] = r1;
    int r2 = U + items[i];
    if (atomicExch(&flags[r2], 1) == 0) rowlist[atomicAdd(nlist, 1)] = r2;
}

// ---------- Bucket histogram (LDS-staged) ----------
__global__ void bhist_kernel(const int* __restrict__ rows, int* __restrict__ bcnt,
                             int n_edges, int NB) {
    __shared__ int h[MAXNB];
    for (int i = threadIdx.x; i < NB; i += blockDim.x) h[i] = 0;
    __syncthreads();
    for (int e = blockIdx.x * blockDim.x + threadIdx.x; e < n_edges;
         e += gridDim.x * blockDim.x)
        atomicAdd(&h[rows[e] >> BSH], 1);
    __syncthreads();
    for (int i = threadIdx.x; i < NB; i += blockDim.x)
        if (h[i]) atomicAdd(&bcnt[i], h[i]);
}

// ---------- Bucket scan (single block, 1024 thr, up to 2048 entries) ----------
__global__ void bscan_kernel(const int* __restrict__ bcnt, int* __restrict__ bstart,
                             int* __restrict__ bfill, int* __restrict__ sbfill,
                             int NB, int n_edges) {
    __shared__ int bufA[MAXNB];
    __shared__ int bufB[MAXNB];
    int tid = threadIdx.x;
    int v0 = (tid < NB) ? bcnt[tid] : 0;
    int v1 = (tid + 1024 < NB) ? bcnt[tid + 1024] : 0;
    bufA[tid] = v0;
    bufA[tid + 1024] = v1;
    __syncthreads();
    int* src = bufA;
    int* dst = bufB;
    for (int off = 1; off < MAXNB; off <<= 1) {
        int j0 = tid, j1 = tid + 1024;
        dst[j0] = src[j0] + (j0 >= off ? src[j0 - off] : 0);
        dst[j1] = src[j1] + (j1 >= off ? src[j1 - off] : 0);
        __syncthreads();
        int* t = src; src = dst; dst = t;
    }
    if (tid < NB) {
        int ex = src[tid] - v0;
        bstart[tid] = ex;
        bfill[tid] = ex;
        if ((tid & ((1 << SBSH) - 1)) == 0) sbfill[tid >> SBSH] = ex;
    }
    if (tid + 1024 < NB) {
        int ex = src[tid + 1024] - v1;
        bstart[tid + 1024] = ex;
        bfill[tid + 1024] = ex;
        if (((tid + 1024) & ((1 << SBSH) - 1)) == 0) sbfill[(tid + 1024) >> SBSH] = ex;
    }
    if (tid == 0) bstart[NB] = n_edges;
}

// ---------- part1: scatter by SUPERBUCKET ----------
// 512 blocks x 1024 threads: full occupancy (2 blocks/CU x 16 waves) WITHOUT
// shrinking the per-block contiguous runs (~105 edges = 840B, amp ~1.08x).
// R13 lesson: run length depends on GRID count, TLP can come from block size.
// payload = (valbits<<32) | ((row>>6)&15)<<26 | (row&63)<<20 | col
__global__ __launch_bounds__(1024) void
part1_kernel(const int* __restrict__ rows, const int* __restrict__ cols,
             const float* __restrict__ vals,
             int* __restrict__ sbfill, long* __restrict__ etmp,
             int n_edges, int NSB) {
    __shared__ int h[MAXNSB];
    int nb_blocks = gridDim.x;
    int c0 = (int)((long)n_edges * blockIdx.x / nb_blocks);
    int c1 = (int)((long)n_edges * (blockIdx.x + 1) / nb_blocks);
    for (int i = threadIdx.x; i < NSB; i += blockDim.x) h[i] = 0;
    __syncthreads();
    for (int e = c0 + threadIdx.x; e < c1; e += blockDim.x)
        atomicAdd(&h[rows[e] >> (BSH + SBSH)], 1);
    __syncthreads();
    for (int i = threadIdx.x; i < NSB; i += blockDim.x)
        if (h[i]) h[i] = atomicAdd(&sbfill[i], h[i]);
    __syncthreads();
    for (int e = c0 + threadIdx.x; e < c1; e += blockDim.x) {
        int r = rows[e];
        int pos = atomicAdd(&h[r >> (BSH + SBSH)], 1);
        etmp[pos] = ((long)(unsigned)__float_as_int(vals[e]) << 32)
                  | (unsigned)(cols[e] | ((r & (BROWS - 1)) << 20)
                               | (((r >> BSH) & ((1 << SBSH) - 1)) << 26));
    }
}

// ---------- part2: within superbucket, scatter by BUCKET (R12 proven shape) ----
__global__ __launch_bounds__(256) void
part2_kernel(const long* __restrict__ etmp, const int* __restrict__ bstart,
             int* __restrict__ bfill, long* __restrict__ edges2, int NB) {
    __shared__ int h[1 << SBSH];
    int sb = blockIdx.x / SBB;
    int j  = blockIdx.x % SBB;
    int b0 = sb << SBSH;
    int b1 = b0 + (1 << SBSH); if (b1 > NB) b1 = NB;
    int s = bstart[b0];
    int t = bstart[b1];
    int m = t - s;
    int c0 = s + (int)((long)m * j / SBB);
    int c1 = s + (int)((long)m * (j + 1) / SBB);
    if (threadIdx.x < (1 << SBSH)) h[threadIdx.x] = 0;
    __syncthreads();
    for (int e = c0 + threadIdx.x; e < c1; e += blockDim.x)
        atomicAdd(&h[((int)etmp[e] >> 26) & ((1 << SBSH) - 1)], 1);
    __syncthreads();
    if (threadIdx.x < (1 << SBSH)) {
        int c = h[threadIdx.x];
        if (c) h[threadIdx.x] = atomicAdd(&bfill[b0 + threadIdx.x], c);
    }
    __syncthreads();
    for (int e = c0 + threadIdx.x; e < c1; e += blockDim.x) {
        long v = etmp[e];
        int pos = atomicAdd(&h[((int)v >> 26) & ((1 << SBSH) - 1)], 1);
        edges2[pos] = v;
    }
}

// ---------- legacy single-pass partition (small-ws fallback) ----------
__global__ __launch_bounds__(256) void
part_legacy_kernel(const int* __restrict__ rows, const int* __restrict__ cols,
                   const float* __restrict__ vals,
                   int* __restrict__ bfill, long* __restrict__ etmp,
                   int n_edges, int NB) {
    __shared__ int h[MAXNB];
    int nb_blocks = gridDim.x;
    int c0 = (int)((long)n_edges * blockIdx.x / nb_blocks);
    int c1 = (int)((long)n_edges * (blockIdx.x + 1) / nb_blocks);
    for (int i = threadIdx.x; i < NB; i += blockDim.x) h[i] = 0;
    __syncthreads();
    for (int e = c0 + threadIdx.x; e < c1; e += blockDim.x)
        atomicAdd(&h[rows[e] >> BSH], 1);
    __syncthreads();
    for (int i = threadIdx.x; i < NB; i += blockDim.x)
        if (h[i]) h[i] = atomicAdd(&bfill[i], h[i]);
    __syncthreads();
    for (int e = c0 + threadIdx.x; e < c1; e += blockDim.x) {
        int r = rows[e];
        int pos = atomicAdd(&h[r >> BSH], 1);
        etmp[pos] = ((long)(unsigned)__float_as_int(vals[e]) << 32)
                  | (unsigned)(cols[e] | ((r & (BROWS - 1)) << 20));
    }
}

// ---------- In-bucket counting sort -> exact CSR (single global read) ----------
__global__ __launch_bounds__(256) void
sort_kernel(const long* __restrict__ ein, const int* __restrict__ bstart,
            long* __restrict__ edges, int* __restrict__ row_start,
            int* __restrict__ cnt, int N) {
    __shared__ long obuf[SCAP];
    __shared__ int h[BROWS];
    __shared__ int fill[BROWS];
    int b = blockIdx.x;
    int s = bstart[b];
    int t = bstart[b + 1];
    int m = t - s;
    int tid = threadIdx.x;
    if (tid < BROWS) h[tid] = 0;
    __syncthreads();
    int row0 = b << BSH;
    if (m <= SCAP) {
        for (int i = tid; i < m; i += 256) {
            long v = ein[s + i];
            obuf[i] = v;
            atomicAdd(&h[((int)v >> 20) & (BROWS - 1)], 1);
        }
        __syncthreads();
        if (tid < BROWS) fill[tid] = h[tid];
        __syncthreads();
        for (int o = 1; o < BROWS; o <<= 1) {
            int v = (tid < BROWS && tid >= o) ? fill[tid - o] : 0;
            __syncthreads();
            if (tid < BROWS) fill[tid] += v;
            __syncthreads();
        }
        if (tid < BROWS) {
            int ex = fill[tid] - h[tid];
            int row = row0 + tid;
            if (row < N) { row_start[row] = s + ex; cnt[row] = h[tid]; }
            fill[tid] = s + ex;
        }
        __syncthreads();
        for (int i = tid; i < m; i += 256) {
            long v = obuf[i];
            int r = ((int)v >> 20) & (BROWS - 1);
            edges[atomicAdd(&fill[r], 1)] = v;
        }
    } else {
        for (int i = tid; i < m; i += 256)
            atomicAdd(&h[((int)ein[s + i] >> 20) & (BROWS - 1)], 1);
        __syncthreads();
        if (tid < BROWS) fill[tid] = h[tid];
        __syncthreads();
        for (int o = 1; o < BROWS; o <<= 1) {
            int v = (tid < BROWS && tid >= o) ? fill[tid - o] : 0;
            __syncthreads();
            if (tid < BROWS) fill[tid] += v;
            __syncthreads();
        }
        if (tid < BROWS) {
            int ex = fill[tid] - h[tid];
            int row = row0 + tid;
            if (row < N) { row_start[row] = s + ex; cnt[row] = h[tid]; }
            fill[tid] = s + ex;
        }
        __syncthreads();
        for (int i = tid; i < m; i += 256) {
            long v = ein[s + i];
            int r = ((int)v >> 20) & (BROWS - 1);
            edges[atomicAdd(&fill[r], 1)] = v;
        }
    }
}

// ---------- Phase 2b (bf16): CSR SpMV, wave per row, bf16 gather mirror ----------
__global__ __launch_bounds__(256) void
spmv_bf_kernel(const long* __restrict__ edges, const int* __restrict__ row_start,
               const int* __restrict__ cnt, const unsigned short* __restrict__ xb,
               float* __restrict__ nxt, unsigned short* __restrict__ xbn, int N) {
    int wid = (int)((long)blockIdx.x * blockDim.x + threadIdx.x) >> 6;
    int row = __builtin_amdgcn_readfirstlane(wid);
    int lane = threadIdx.x & 63;
    if (row >= N) return;
    int s = __builtin_amdgcn_readfirstlane(row_start[row]);
    int n = __builtin_amdgcn_readfirstlane(cnt[row]);
    const long* ep = edges + s;
    float sum = 0.f;
    int e = 0;
    for (; e + 16 <= n; e += 16) {
        long q[16];
        float g[16];
        #pragma unroll
        for (int j = 0; j < 16; ++j) q[j] = ep[e + j];
        #pragma unroll
        for (int j = 0; j < 16; ++j)
            g[j] = bf2f(xb[(long)((int)q[j] & 0xFFFFF) * D + lane]);
        #pragma unroll
        for (int j = 0; j < 16; ++j) sum += __int_as_float((int)(q[j] >> 32)) * g[j];
    }
    for (; e + 4 <= n; e += 4) {
        long q[4];
        float g[4];
        #pragma unroll
        for (int j = 0; j < 4; ++j) q[j] = ep[e + j];
        #pragma unroll
        for (int j = 0; j < 4; ++j)
            g[j] = bf2f(xb[(long)((int)q[j] & 0xFFFFF) * D + lane]);
        #pragma unroll
        for (int j = 0; j < 4; ++j) sum += __int_as_float((int)(q[j] >> 32)) * g[j];
    }
    for (; e < n; ++e) {
        long q = ep[e];
        sum += __int_as_float((int)(q >> 32)) * bf2f(xb[(long)((int)q & 0xFFFFF) * D + lane]);
    }
    long o = (long)row * D + lane;
    __builtin_nontemporal_store(sum, &nxt[o]);
    xbn[o] = f2bf(sum);
}

// ---------- Phase 2c (bf16): sparse layer 3, wave per LISTED row ----------
__global__ __launch_bounds__(256) void
spmv_list_bf_kernel(const long* __restrict__ edges, const int* __restrict__ row_start,
                    const int* __restrict__ cnt, const int* __restrict__ rowlist,
                    const int* __restrict__ nlist, const unsigned short* __restrict__ xb,
                    float* __restrict__ nxt) {
    int wid = (int)((long)blockIdx.x * blockDim.x + threadIdx.x) >> 6;
    int nl = __builtin_amdgcn_readfirstlane(nlist[0]);
    if (wid >= nl) return;
    int row = __builtin_amdgcn_readfirstlane(rowlist[wid]);
    int lane = threadIdx.x & 63;
    int s = __builtin_amdgcn_readfirstlane(row_start[row]);
    int n = __builtin_amdgcn_readfirstlane(cnt[row]);
    const long* ep = edges + s;
    float sum = 0.f;
    int e = 0;
    for (; e + 16 <= n; e += 16) {
        long q[16];
        float g[16];
        #pragma unroll
        for (int j = 0; j < 16; ++j) q[j] = ep[e + j];
        #pragma unroll
        for (int j = 0; j < 16; ++j)
            g[j] = bf2f(xb[(long)((int)q[j] & 0xFFFFF) * D + lane]);
        #pragma unroll
        for (int j = 0; j < 16; ++j) sum += __int_as_float((int)(q[j] >> 32)) * g[j];
    }
    for (; e + 4 <= n; e += 4) {
        long q[4];
        float g[4];
        #pragma unroll
        for (int j = 0; j < 4; ++j) q[j] = ep[e + j];
        #pragma unroll
        for (int j = 0; j < 4; ++j)
            g[j] = bf2f(xb[(long)((int)q[j] & 0xFFFFF) * D + lane]);
        #pragma unroll
        for (int j = 0; j < 4; ++j) sum += __int_as_float((int)(q[j] >> 32)) * g[j];
    }
    for (; e < n; ++e) {
        long q = ep[e];
        sum += __int_as_float((int)(q >> 32)) * bf2f(xb[(long)((int)q & 0xFFFFF) * D + lane]);
    }
    __builtin_nontemporal_store(sum, &nxt[(long)row * D + lane]);
}

// ---------- Phase 2b (f32 fallback): CSR SpMV, wave per row ----------
__global__ __launch_bounds__(256) void
spmv_kernel(const long* __restrict__ edges, const int* __restrict__ row_start,
            const int* __restrict__ cnt, const float* __restrict__ x,
            float* __restrict__ nxt, float* __restrict__ acc, int N) {
    int wid = (int)((long)blockIdx.x * blockDim.x + threadIdx.x) >> 6;
    int row = __builtin_amdgcn_readfirstlane(wid);
    int lane = threadIdx.x & 63;
    if (row >= N) return;
    int s = __builtin_amdgcn_readfirstlane(row_start[row]);
    int n = __builtin_amdgcn_readfirstlane(cnt[row]);
    const long* ep = edges + s;
    float sum = 0.f;
    int e = 0;
    for (; e + 16 <= n; e += 16) {
        long q[16];
        float g[16];
        #pragma unroll
        for (int j = 0; j < 16; ++j) q[j] = ep[e + j];
        #pragma unroll
        for (int j = 0; j < 16; ++j) g[j] = x[(long)((int)q[j] & 0xFFFFF) * D + lane];
        #pragma unroll
        for (int j = 0; j < 16; ++j) sum += __int_as_float((int)(q[j] >> 32)) * g[j];
    }
    for (; e + 4 <= n; e += 4) {
        long q[4];
        float g[4];
        #pragma unroll
        for (int j = 0; j < 4; ++j) q[j] = ep[e + j];
        #pragma unroll
        for (int j = 0; j < 4; ++j) g[j] = x[(long)((int)q[j] & 0xFFFFF) * D + lane];
        #pragma unroll
        for (int j = 0; j < 4; ++j) sum += __int_as_float((int)(q[j] >> 32)) * g[j];
    }
    for (; e < n; ++e) {
        long q = ep[e];
        sum += __int_as_float((int)(q >> 32)) * x[(long)((int)q & 0xFFFFF) * D + lane];
    }
    long o = (long)row * D + lane;
    if (acc) { nxt[o] = sum; acc[o] += sum; }
    else __builtin_nontemporal_store(sum, &nxt[o]);
}

// ---------- Phase 2c (f32 fallback): sparse layer 3 ----------
__global__ __launch_bounds__(256) void
spmv_list_kernel(const long* __restrict__ edges, const int* __restrict__ row_start,
                 const int* __restrict__ cnt, const int* __restrict__ rowlist,
                 const int* __restrict__ nlist, const float* __restrict__ x,
                 float* __restrict__ nxt, float* __restrict__ acc) {
    int wid = (int)((long)blockIdx.x * blockDim.x + threadIdx.x) >> 6;
    int nl = __builtin_amdgcn_readfirstlane(nlist[0]);
    if (wid >= nl) return;
    int row = __builtin_amdgcn_readfirstlane(rowlist[wid]);
    int lane = threadIdx.x & 63;
    int s = __builtin_amdgcn_readfirstlane(row_start[row]);
    int n = __builtin_amdgcn_readfirstlane(cnt[row]);
    const long* ep = edges + s;
    float sum = 0.f;
    int e = 0;
    for (; e + 16 <= n; e += 16) {
        long q[16];
        float g[16];
        #pragma unroll
        for (int j = 0; j < 16; ++j) q[j] = ep[e + j];
        #pragma unroll
        for (int j = 0; j < 16; ++j) g[j] = x[(long)((int)q[j] & 0xFFFFF) * D + lane];
        #pragma unroll
        for (int j = 0; j < 16; ++j) sum += __int_as_float((int)(q[j] >> 32)) * g[j];
    }
    for (; e + 4 <= n; e += 4) {
        long q[4];
        float g[4];
        #pragma unroll
        for (int j = 0; j < 4; ++j) q[j] = ep[e + j];
        #pragma unroll
        for (int j = 0; j < 4; ++j) g[j] = x[(long)((int)q[j] & 0xFFFFF) * D + lane];
        #pragma unroll
        for (int j = 0; j < 4; ++j) sum += __int_as_float((int)(q[j] >> 32)) * g[j];
    }
    for (; e < n; ++e) {
        long q = ep[e];
        sum += __int_as_float((int)(q >> 32)) * x[(long)((int)q & 0xFFFFF) * D + lane];
    }
    long o = (long)row * D + lane;
    if (acc) { nxt[o] = sum; acc[o] += sum; }
    else __builtin_nontemporal_store(sum, &nxt[o]);
}

// ---------- Phase 3: gamma = dot of layer-mean embeddings ----------
__global__ void dot_kernel(const float* __restrict__ x0, const float* __restrict__ x1,
                           const float* __restrict__ x2, const float* __restrict__ x3,
                           const float* __restrict__ acc,
                           const int* __restrict__ users, const int* __restrict__ items,
                           float* __restrict__ out, int U, int B) {
    int wave = (blockIdx.x * blockDim.x + threadIdx.x) >> 6;
    int lane = threadIdx.x & 63;
    if (wave >= B) return;
    long ou = (long)users[wave] * D + lane;
    long oi = (long)(U + items[wave]) * D + lane;
    float su, si;
    if (acc) {
        su = acc[ou];
        si = acc[oi];
    } else {
        su = x0[ou] + x1[ou] + x2[ou] + x3[ou];
        si = x0[oi] + x1[oi] + x2[oi] + x3[oi];
    }
    float p = su * si;
    #pragma unroll
    for (int off = 32; off > 0; off >>= 1) p += __shfl_xor(p, off, 64);
    if (lane == 0) out[wave] = p * 0.0625f;
}

extern "C" void kernel_launch(void* const* d_in, const int* in_sizes, int n_in,
                              void* d_out, int out_size, void* d_ws, size_t ws_size,
                              hipStream_t stream) {
    const int*   users    = (const int*)  d_in[0];
    const int*   items    = (const int*)  d_in[1];
    const int*   g_rows   = (const int*)  d_in[2];
    const int*   g_cols   = (const int*)  d_in[3];
    const float* g_vals   = (const float*)d_in[4];
    const float* user_emb = (const float*)d_in[5];
    const float* item_emb = (const float*)d_in[6];
    const float* ent_emb  = (const float*)d_in[7];
    const float* rel_emb  = (const float*)d_in[8];
    const int*   kg_e     = (const int*)  d_in[9];
    const int*   kg_r     = (const int*)  d_in[10];
    const float* fc_W     = (const float*)d_in[11];
    const float* fc_b     = (const float*)d_in[12];
    float* out = (float*)d_out;

    int B       = in_sizes[0];
    int n_edges = in_sizes[2];
    int U       = in_sizes[5] / D;
    int I       = in_sizes[6] / D;
    int NE1     = in_sizes[7] / D;   // E_ENT + 1
    int NR      = in_sizes[8] / D;   // R + 1
    int K       = in_sizes[9] / I;
    int N  = U + I;
    int ND = N * D;
    int NB = (N + BROWS - 1) >> BSH;       // 1172 buckets (<= MAXNB)
    int NSB = (NB + (1 << SBSH) - 1) >> SBSH;  // 74 superbuckets (<= MAXNSB)

    size_t small = (size_t)(2 * NR * D + NR + 3 * (NB + 1) + MAXNSB + 4 * N + 1) * 4 + 8192;
    size_t need_def = 4ul * ND * 4 + (size_t)n_edges * 8 + small;
    size_t need_bf  = need_def + 2ul * ND * 2 + 512;
    int deferred = (need_def <= ws_size);
    int usebf    = (need_bf <= ws_size);

    char* basep = (char*)d_ws;
    size_t woff = 0;
    auto alloc = [&](size_t bytes) -> char* {
        char* p = basep + woff;
        woff = (woff + bytes + 255) & ~(size_t)255;
        return p;
    };

    float *x0, *x1, *x2, *x3, *acc;
    long *etmp, *edges2;
    unsigned short *xb0 = nullptr, *xb1 = nullptr;
    if (deferred) {
        x0 = (float*)alloc((size_t)ND * 4);
        x1 = (float*)alloc((size_t)ND * 4);
        x2 = (float*)alloc((size_t)ND * 4);
        x3 = (float*)alloc((size_t)ND * 4);
        acc = nullptr;
        etmp   = (long*)x0;             // x0+x1 span 38.4MB >= 32MB; dead after part2
        edges2 = (long*)x2;             // x2+x3 span; dead after sort
        if (usebf) {
            xb0 = (unsigned short*)alloc((size_t)ND * 2);
            xb1 = (unsigned short*)alloc((size_t)ND * 2);
        }
    } else {
        x0 = (float*)alloc((size_t)ND * 4);
        x1 = (float*)alloc((size_t)ND * 4);
        x2 = x0; x3 = x1;               // ping-pong
        acc = (float*)alloc((size_t)ND * 4);
        etmp   = (long*)x0;
        edges2 = nullptr;
        usebf = 0;
    }
    float* w1r      = (float*)alloc((size_t)NR * D * 4);
    float* w2r      = (float*)alloc((size_t)NR * D * 4);
    float* br       = (float*)alloc((size_t)NR * 4);
    int*   bcnt     = (int*)  alloc((size_t)(NB + 1) * 4);
    int*   bstart   = (int*)  alloc((size_t)(NB + 1) * 4);
    int*   bfill    = (int*)  alloc((size_t)(NB + 1) * 4);
    int*   sbfill   = (int*)  alloc((size_t)MAXNSB * 4);
    int*   row_start= (int*)  alloc((size_t)N * 4);
    int*   cnt      = (int*)  alloc((size_t)N * 4);
    int*   flags    = (int*)  alloc((size_t)(N + 1) * 4);  // +1: nlist counter
    int*   rowlist  = (int*)  alloc((size_t)N * 4);
    int*   nlist    = flags + N;
    long*  edges    = (long*) alloc((size_t)n_edges * 8);

    // ---- CSR build (etmp/edges2 occupy layer-buffer space; runs first) ----
    hipMemsetAsync(bcnt, 0, (size_t)(NB + 1) * 4, stream);
    bhist_kernel<<<1024, 256, 0, stream>>>(g_rows, bcnt, n_edges, NB);
    bscan_kernel<<<1, 1024, 0, stream>>>(bcnt, bstart, bfill, sbfill, NB, n_edges);
    if (deferred) {
        part1_kernel<<<512, 1024, 0, stream>>>(g_rows, g_cols, g_vals, sbfill, etmp,
                                               n_edges, NSB);
        part2_kernel<<<NSB * SBB, 256, 0, stream>>>(etmp, bstart, bfill, edges2, NB);
        sort_kernel<<<NB, 256, 0, stream>>>(edges2, bstart, edges, row_start, cnt, N);
    } else {
        part_legacy_kernel<<<512, 256, 0, stream>>>(g_rows, g_cols, g_vals, bfill, etmp,
                                                    n_edges, NB);
        sort_kernel<<<NB, 256, 0, stream>>>(etmp, bstart, edges, row_start, cnt, N);
    }

    // ---- flags/rowlist zero (for mark) ----
    hipMemsetAsync(flags, 0, (size_t)(N + 1) * 4, stream);

    // Phase 0 + 1: GAT (writes x0 items f32 + bf16 mirror in bf mode)
    relpre_kernel<<<NR, D, 0, stream>>>(fc_W, fc_b, rel_emb, w1r, w2r, br);
    unsigned short* xb_items = usebf ? xb0 + (long)U * D : nullptr;
    if (K == 16) {
        gat16_kernel<<<(I + 3) / 4, 256, 0, stream>>>(item_emb, ent_emb, kg_e, kg_r,
                                                      w1r, w2r, br,
                                                      x0 + (long)U * D, xb_items, I, NE1 - 1);
    } else {
        gat_kernel<<<(I + 3) / 4, 256, 0, stream>>>(item_emb, ent_emb, kg_e, kg_r,
                                                    w1r, w2r, br,
                                                    x0 + (long)U * D, xb_items, I, K, NE1 - 1);
    }

    // Phase 2a: user half of x0 (+ mirror) + batch-row mark/compact
    if (deferred) {
        int n4 = U * D / 4;
        int g = n4 > B ? n4 : B;
        initmark_kernel<<<(g + 255) / 256, 256, 0, stream>>>(user_emb, x0,
                                                             usebf ? xb0 : nullptr,
                                                             users, items,
                                                             flags, rowlist, nlist, U, B, n4);
    } else {
        init_kernel<<<2048, 256, 0, stream>>>(user_emb, x0, acc, U * D, ND);
        mark_kernel<<<(B + 255) / 256, 256, 0, stream>>>(users, items, flags, rowlist,
                                                         nlist, U, B);
    }

    // Phase 2b/2c: LightGCN layers
    long total = (long)N * 64;
    int blocks = (int)((total + 255) / 256);
    int maxrows = (2 * B < N) ? 2 * B : N;
    int lblocks = (int)(((long)maxrows * 64 + 255) / 256);
    if (usebf) {
        spmv_bf_kernel<<<blocks, 256, 0, stream>>>(edges, row_start, cnt, xb0, x1, xb1, N);
        spmv_bf_kernel<<<blocks, 256, 0, stream>>>(edges, row_start, cnt, xb1, x2, xb0, N);
        spmv_list_bf_kernel<<<lblocks, 256, 0, stream>>>(edges, row_start, cnt, rowlist,
                                                         nlist, xb0, x3);
    } else {
        spmv_kernel<<<blocks, 256, 0, stream>>>(edges, row_start, cnt, x0, x1, acc, N);
        spmv_kernel<<<blocks, 256, 0, stream>>>(edges, row_start, cnt, x1, x2, acc, N);
        spmv_list_kernel<<<lblocks, 256, 0, stream>>>(edges, row_start, cnt, rowlist, nlist,
                                                      x2, x3, acc);
    }

    // Phase 3: batch dot (f32 layer buffers, unchanged)
    dot_kernel<<<(B + 3) / 4, 256, 0, stream>>>(x0, x1, x2, x3, acc, users, items, out, U, B);
}